// Round 2
// baseline (434.806 us; speedup 1.0000x reference)
//
#include <hip/hip_runtime.h>

// LocalLayer: y = x @ W^T + b, W banded: output window k (16 outputs) reads
// input cols [16k-32, 16k+32). Banded GEMM = 4.3 GFLOP -> HBM-bound,
// floor ~ writes 136 MB + reads ~70-160 MB => ~35-40 us.
//
// R2: barrier-free / LDS-free. MFMA A-frag (lane n16,quad) = 8 contiguous
// k-elems of row n16 -> load directly from global x (2x float4) + in-reg
// bf16 cvt. Window w uses F(w-2),F(w) where F(p)=cols[16p,16p+32); F shared
// between windows w and w+2 -> 2-deep rolling register pipeline, x read
// once per wave. No LDS, no __syncthreads, waves stream independently.

typedef __attribute__((ext_vector_type(8))) short short8;
typedef __attribute__((ext_vector_type(4))) float f32x4;

#define IN_F 4096
#define OUT_F 4096
#define NROWS 8192
#define GW 16     // windows per wave strip (256 output cols)

__device__ __forceinline__ unsigned short f2bf(float f) {
  unsigned int u = __float_as_uint(f);
  u += 0x7FFFu + ((u >> 16) & 1u);   // round-to-nearest-even
  return (unsigned short)(u >> 16);
}

// Pack banded W into MFMA B-fragment order, bf16.
// Fragment f = win*2 + t. Lane: n = lane&15 (output col within window),
// quad = lane>>4, k = quad*8 + j. W column = win*16 - 32 + t*32 + quad*8 + j,
// zero outside [0, IN_F). Store at Wp[tid*8 + j].
__global__ void pack_w_kernel(const float* __restrict__ W,
                              unsigned short* __restrict__ Wp) {
  int tid = blockIdx.x * 256 + threadIdx.x;  // 32768 threads total
  int lane = tid & 63;
  int t = (tid >> 6) & 1;
  int win = tid >> 7;
  int n = lane & 15, quad = lane >> 4;
  int o = win * 16 + n;
  int cbase = win * 16 - 32 + t * 32 + quad * 8;
  short8 h;
#pragma unroll
  for (int j = 0; j < 8; ++j) {
    int c = cbase + j;
    float v = (c >= 0 && c < IN_F) ? W[o * IN_F + c] : 0.0f;
    h[j] = (short)f2bf(v);
  }
  *(short8*)(Wp + (size_t)tid * 8) = h;
}

// Load A-fragment F(p) for this lane: 8 floats of row xr at col 16p+quad*8,
// converted to bf16. Zero outside [0, IN_F) (packed W is zero there too).
__device__ __forceinline__ short8 load_frag(const float* __restrict__ xr,
                                            int p, int quad) {
  int c0 = 16 * p + quad * 8;       // multiple of 8, may be negative
  float4 v0 = make_float4(0.f, 0.f, 0.f, 0.f);
  float4 v1 = make_float4(0.f, 0.f, 0.f, 0.f);
  if (c0 >= 0 && c0 <= IN_F - 4) v0 = *(const float4*)(xr + c0);
  if (c0 + 4 >= 0 && c0 + 4 <= IN_F - 4) v1 = *(const float4*)(xr + c0 + 4);
  short8 h;
  h[0] = (short)f2bf(v0.x); h[1] = (short)f2bf(v0.y);
  h[2] = (short)f2bf(v0.z); h[3] = (short)f2bf(v0.w);
  h[4] = (short)f2bf(v1.x); h[5] = (short)f2bf(v1.y);
  h[6] = (short)f2bf(v1.z); h[7] = (short)f2bf(v1.w);
  return h;
}

__global__ __launch_bounds__(256, 4) void local_gemm_kernel(
    const float* __restrict__ x, const unsigned short* __restrict__ Wp,
    const float* __restrict__ bias, float* __restrict__ out) {
  const int tid = threadIdx.x;
  const int lane = tid & 63;
  const int wave = tid >> 6;       // 4 waves = 4 row tiles of 16
  const int n16 = lane & 15;
  const int quad = lane >> 4;
  const int wg = blockIdx.y;       // window group: 16 windows = 256 cols
  const int w0 = wg * GW;
  const int arow = blockIdx.x * 64 + wave * 16 + n16;  // this lane's A row

  const float* xr = x + (size_t)arow * IN_F;
  const short8* wpv = (const short8*)Wp;

  f32x4 acc[GW];
#pragma unroll
  for (int wl = 0; wl < GW; ++wl) {
    float bv = bias[wg * 256 + wl * 16 + n16];
    acc[wl] = (f32x4){bv, bv, bv, bv};
  }

  // Rolling A-fragment pipeline: window w needs F(w-2) and F(w).
  short8 a_m2 = load_frag(xr, w0 - 2, quad);
  short8 a_m1 = load_frag(xr, w0 - 1, quad);
#pragma unroll 4
  for (int wl = 0; wl < GW; ++wl) {
    int win = w0 + wl;
    short8 cur = load_frag(xr, win, quad);
    short8 b0 = wpv[(win * 2 + 0) * 64 + lane];  // cols [16win-32,16win)
    short8 b1 = wpv[(win * 2 + 1) * 64 + lane];  // cols [16win,16win+32)
    acc[wl] = __builtin_amdgcn_mfma_f32_16x16x32_bf16(a_m2, b0, acc[wl], 0, 0, 0);
    acc[wl] = __builtin_amdgcn_mfma_f32_16x16x32_bf16(cur, b1, acc[wl], 0, 0, 0);
    a_m2 = a_m1;
    a_m1 = cur;
  }

  // C/D layout: col = lane&15, row = quad*4 + reg  [m89]
  float* op = out + (size_t)(blockIdx.x * 64 + wave * 16 + quad * 4) * OUT_F +
              wg * 256 + n16;
#pragma unroll
  for (int wl = 0; wl < GW; ++wl) {
#pragma unroll
    for (int r = 0; r < 4; ++r) op[r * OUT_F + wl * 16] = acc[wl][r];
  }
}

extern "C" void kernel_launch(void* const* d_in, const int* in_sizes, int n_in,
                              void* d_out, int out_size, void* d_ws, size_t ws_size,
                              hipStream_t stream) {
  const float* x = (const float*)d_in[0];
  const float* W = (const float*)d_in[1];
  const float* b = (const float*)d_in[2];
  // d_in[3] = mask, unused (band structure is compile-time known)
  float* out = (float*)d_out;
  unsigned short* Wp = (unsigned short*)d_ws;  // 512 KB, L2/L3-resident

  hipLaunchKernelGGL(pack_w_kernel, dim3(128), dim3(256), 0, stream, W, Wp);
  hipLaunchKernelGGL(local_gemm_kernel, dim3(NROWS / 64, 256 / GW), dim3(256),
                     0, stream, x, Wp, b, out);
}

// Round 3
// 346.185 us; speedup vs baseline: 1.2560x; 1.2560x over previous
//
#include <hip/hip_runtime.h>

// LocalLayer: y = x @ W^T + b, W banded: output window k (16 outputs) reads
// input cols [16k-32, 16k+32). Banded GEMM = 4.3 GFLOP -> HBM-bound,
// floor ~ writes 136 MB + reads ~70-160 MB => ~35-40 us.
//
// R3: R2's barrier-free/LDS-free structure with the acc-spill fixed.
// R2's "#pragma unroll 4" left acc[wl] dynamically indexed -> compiler
// demoted the accumulator array to scratch (VGPR 32, +260 MB scratch
// writes). FULL unroll keeps acc[] in AGPRs (indices compile-time).

typedef __attribute__((ext_vector_type(8))) short short8;
typedef __attribute__((ext_vector_type(4))) float f32x4;

#define IN_F 4096
#define OUT_F 4096
#define NROWS 8192
#define GW 16     // windows per wave strip (256 output cols)

__device__ __forceinline__ unsigned short f2bf(float f) {
  unsigned int u = __float_as_uint(f);
  u += 0x7FFFu + ((u >> 16) & 1u);   // round-to-nearest-even
  return (unsigned short)(u >> 16);
}

// Pack banded W into MFMA B-fragment order, bf16.
// Fragment f = win*2 + t. Lane: n = lane&15 (output col within window),
// quad = lane>>4, k = quad*8 + j. W column = win*16 - 32 + t*32 + quad*8 + j,
// zero outside [0, IN_F). Store at Wp[tid*8 + j].
__global__ void pack_w_kernel(const float* __restrict__ W,
                              unsigned short* __restrict__ Wp) {
  int tid = blockIdx.x * 256 + threadIdx.x;  // 32768 threads total
  int lane = tid & 63;
  int t = (tid >> 6) & 1;
  int win = tid >> 7;
  int n = lane & 15, quad = lane >> 4;
  int o = win * 16 + n;
  int cbase = win * 16 - 32 + t * 32 + quad * 8;
  short8 h;
#pragma unroll
  for (int j = 0; j < 8; ++j) {
    int c = cbase + j;
    float v = (c >= 0 && c < IN_F) ? W[o * IN_F + c] : 0.0f;
    h[j] = (short)f2bf(v);
  }
  *(short8*)(Wp + (size_t)tid * 8) = h;
}

// Load A-fragment F(p) for this lane: 8 floats of row xr at col 16p+quad*8,
// converted to bf16. Zero outside [0, IN_F) (packed W is zero there too).
__device__ __forceinline__ short8 load_frag(const float* __restrict__ xr,
                                            int p, int quad) {
  int c0 = 16 * p + quad * 8;       // multiple of 8, may be negative
  float4 v0 = make_float4(0.f, 0.f, 0.f, 0.f);
  float4 v1 = make_float4(0.f, 0.f, 0.f, 0.f);
  if (c0 >= 0 && c0 <= IN_F - 4) v0 = *(const float4*)(xr + c0);
  if (c0 + 4 >= 0 && c0 + 4 <= IN_F - 4) v1 = *(const float4*)(xr + c0 + 4);
  short8 h;
  h[0] = (short)f2bf(v0.x); h[1] = (short)f2bf(v0.y);
  h[2] = (short)f2bf(v0.z); h[3] = (short)f2bf(v0.w);
  h[4] = (short)f2bf(v1.x); h[5] = (short)f2bf(v1.y);
  h[6] = (short)f2bf(v1.z); h[7] = (short)f2bf(v1.w);
  return h;
}

__global__ __launch_bounds__(256, 4) void local_gemm_kernel(
    const float* __restrict__ x, const unsigned short* __restrict__ Wp,
    const float* __restrict__ bias, float* __restrict__ out) {
  const int tid = threadIdx.x;
  const int lane = tid & 63;
  const int wave = tid >> 6;       // 4 waves = 4 row tiles of 16
  const int n16 = lane & 15;
  const int quad = lane >> 4;
  const int wg = blockIdx.y;       // window group: 16 windows = 256 cols
  const int w0 = wg * GW;
  const int arow = blockIdx.x * 64 + wave * 16 + n16;  // this lane's A row

  const float* xr = x + (size_t)arow * IN_F;
  const short8* wpv = (const short8*)Wp;

  f32x4 acc[GW];
#pragma unroll
  for (int wl = 0; wl < GW; ++wl) {
    float bv = bias[wg * 256 + wl * 16 + n16];
    acc[wl] = (f32x4){bv, bv, bv, bv};
  }

  // Rolling A-fragment pipeline: window w needs F(w-2) and F(w), F shared
  // between windows w and w+2. FULL unroll: acc[] indices must be
  // compile-time constants or the array spills to scratch (R2 lesson).
  short8 a_m2 = load_frag(xr, w0 - 2, quad);
  short8 a_m1 = load_frag(xr, w0 - 1, quad);
#pragma unroll
  for (int wl = 0; wl < GW; ++wl) {
    int win = w0 + wl;
    short8 cur = load_frag(xr, win, quad);
    short8 b0 = wpv[(win * 2 + 0) * 64 + lane];  // cols [16win-32,16win)
    short8 b1 = wpv[(win * 2 + 1) * 64 + lane];  // cols [16win,16win+32)
    acc[wl] = __builtin_amdgcn_mfma_f32_16x16x32_bf16(a_m2, b0, acc[wl], 0, 0, 0);
    acc[wl] = __builtin_amdgcn_mfma_f32_16x16x32_bf16(cur, b1, acc[wl], 0, 0, 0);
    a_m2 = a_m1;
    a_m1 = cur;
  }

  // C/D layout: col = lane&15, row = quad*4 + reg  [m89]
  float* op = out + (size_t)(blockIdx.x * 64 + wave * 16 + quad * 4) * OUT_F +
              wg * 256 + n16;
#pragma unroll
  for (int wl = 0; wl < GW; ++wl) {
#pragma unroll
    for (int r = 0; r < 4; ++r) op[r * OUT_F + wl * 16] = acc[wl][r];
  }
}

extern "C" void kernel_launch(void* const* d_in, const int* in_sizes, int n_in,
                              void* d_out, int out_size, void* d_ws, size_t ws_size,
                              hipStream_t stream) {
  const float* x = (const float*)d_in[0];
  const float* W = (const float*)d_in[1];
  const float* b = (const float*)d_in[2];
  // d_in[3] = mask, unused (band structure is compile-time known)
  float* out = (float*)d_out;
  unsigned short* Wp = (unsigned short*)d_ws;  // 512 KB, L2/L3-resident

  hipLaunchKernelGGL(pack_w_kernel, dim3(128), dim3(256), 0, stream, W, Wp);
  hipLaunchKernelGGL(local_gemm_kernel, dim3(NROWS / 64, 256 / GW), dim3(256),
                     0, stream, x, Wp, b, out);
}